// Round 1
// 2050.626 us; speedup vs baseline: 1.0254x; 1.0254x over previous
//
#include <hip/hip_runtime.h>
#include <math.h>

// Problem constants: B=8192, S=2TX=64, F=65, HID=128, 3H=384, DIMZ=64, DIRS=2
// GD_STEP=1e-6 (two_step=2e-6), GD_ITERS=10, BN_EPS=1e-5

typedef __attribute__((ext_vector_type(8))) short s8v;   // 8 x bf16 (MFMA A/B frag)
typedef __attribute__((ext_vector_type(4))) float f4v;   // MFMA C/D frag

__device__ __forceinline__ short f2bf(float x) {         // RNE float->bf16
  unsigned u = __float_as_uint(x);
  u += 0x7fffu + ((u >> 16) & 1u);
  return (short)(u >> 16);
}
__device__ __forceinline__ float bf2f(short h) {
  return __uint_as_float(((unsigned)(unsigned short)h) << 16);
}
__device__ __forceinline__ void fma4(float4& c, float a, const float4 w) {
  c.x += a*w.x; c.y += a*w.y; c.z += a*w.z; c.w += a*w.w;
}
__device__ __forceinline__ float vget(const float4& v, int i) { return ((const float*)&v)[i]; }

#define MFMA(A, B, C) __builtin_amdgcn_mfma_f32_16x16x32_bf16((A), (B), (C), 0, 0, 0)

// ---------------------------------------------------------------------------
// K1: per-batch HtH -> UNSCALED split-bf16 fragX (A-frag order), htyU[s][b],
// BN stat partials. fragX elem (b,s,k): tile=b>>6, mt=(b>>4)&3, chunk kt=k>>5,
// lane=(b&15)+16*((k>>3)&3), i=k&7; hi at chunk*512+lane*8+i, lo at +4096.
// ---------------------------------------------------------------------------
__global__ __launch_bounds__(256) void k_feats(
    const float* __restrict__ Hm, const float* __restrict__ y,
    short* __restrict__ fragX, float* __restrict__ htyU, float* __restrict__ bnacc)
{
  __shared__ __align__(16) float Hl[64][68];
  __shared__ float yl[64];
  __shared__ float s1[64], s2[64];
  const int b = blockIdx.x;
  const int tid = threadIdx.x;
  const float* Hb = Hm + (size_t)b*4096;
  for (int i = tid; i < 4096; i += 256) Hl[i>>6][i&63] = Hb[i];
  if (tid < 64) { yl[tid] = y[b*64+tid]; s1[tid] = 0.f; s2[tid] = 0.f; }
  __syncthreads();

  if (tid < 64) {                       // Hty channel (f=64), unscaled, [s][b]
    float acc = 0.f;
    for (int r = 0; r < 64; ++r) acc += Hl[r][tid]*yl[r];
    htyU[tid*8192 + b] = acc;
    atomicAdd(&s1[tid], acc);
    atomicAdd(&s2[tid], acc*acc);
  }
  const int tg = tid & 15, ug = tid >> 4;
  float4 acc4[4];
  acc4[0]=acc4[1]=acc4[2]=acc4[3]=make_float4(0.f,0.f,0.f,0.f);
  for (int r = 0; r < 64; ++r) {        // HtH[t=4tg+tt][u=4ug+uu]
    const float4 tv = *(const float4*)&Hl[r][4*tg];
    const float4 uv = *(const float4*)&Hl[r][4*ug];
    #pragma unroll
    for (int tt=0;tt<4;++tt) fma4(acc4[tt], vget(tv,tt), uv);
  }
  // frag-store geometry (u = 4ug..4ug+3 -> 4 consecutive shorts in one group)
  const int mt   = (b >> 4) & 3;
  const int brow = b & 15;
  const int u0   = 4*ug;
  short* fbase = fragX + (size_t)(b >> 6)*64*8192
               + (mt*2 + (u0 >> 5))*512 + (brow + 16*((u0 >> 3) & 3))*8 + (u0 & 7);
  #pragma unroll
  for (int tt=0;tt<4;++tt) {
    const int t = 4*tg+tt;              // t == seq channel s
    float sv=0.f, sq=0.f;
    short hib[4], lob[4];
    #pragma unroll
    for (int uu=0;uu<4;++uu) {
      const float v = vget(acc4[tt],uu);
      const short hi = f2bf(v);
      hib[uu] = hi; lob[uu] = f2bf(v - bf2f(hi));
      sv += v; sq += v*v;
    }
    short* dst = fbase + (size_t)t*8192;
    *(short4*)dst          = make_short4(hib[0],hib[1],hib[2],hib[3]);
    *(short4*)(dst + 4096) = make_short4(lob[0],lob[1],lob[2],lob[3]);
    sv += __shfl_down(sv,32); sq += __shfl_down(sq,32);
    sv += __shfl_down(sv,16); sq += __shfl_down(sq,16);
    if ((tid & 63) < 16) { atomicAdd(&s1[t], sv); atomicAdd(&s2[t], sq); }
  }
  __syncthreads();
  if (tid < 64) {
    atomicAdd(&bnacc[tid*16],      s1[tid]);
    atomicAdd(&bnacc[(64+tid)*16], s2[tid]);
  }
}

// ---------------------------------------------------------------------------
// K2a: BN finalize -> a[t]=gamma/sqrt(var+eps), c[t]=beta-mu*a
// ---------------------------------------------------------------------------
__global__ void k_bnfin(const float* __restrict__ bnacc, const float* __restrict__ gam,
                        const float* __restrict__ bet, float* __restrict__ bnac)
{
  const int t = threadIdx.x;
  if (t < 64) {
    const float inv = 1.f/532480.f;           // B*F = 8192*65
    const float mu  = bnacc[t*16]*inv;
    const float var = bnacc[(64+t)*16]*inv - mu*mu;
    const float a = gam[t]*rsqrtf(var + 1e-5f);
    bnac[t] = a;
    bnac[64+t] = bet[t] - mu*a;
  }
}

// ---------------------------------------------------------------------------
// K2b: split-bf16 weight images in MFMA B-frag order + wih row sums
// Wg:  [d][sp][nt(24)][kt(6)][512]  (k: 0..63=f(wih), 64..191=j(whh))
// W2g: [d][sp][nt2(8)][kt(4)][512]  (n2: 0..63=Wx row, 64..127=Wz row)
// ---------------------------------------------------------------------------
__global__ __launch_bounds__(256) void k_prep(
    const float* __restrict__ wih, const float* __restrict__ whh,
    const float* __restrict__ Wz, const float* __restrict__ Wx,
    short* __restrict__ Wg, short* __restrict__ W2g, float* __restrict__ rowsum)
{
  const int i = blockIdx.x*256 + threadIdx.x;
  if (i < 294912) {
    const int dd = i / 147456, r = i % 147456;
    const int sp = r / 73728, r2 = r % 73728;
    const int chunk = r2 / 512, e = r2 % 512;
    const int lane = e >> 3, ii = e & 7;
    const int nt = chunk / 6, kt = chunk % 6;
    const int n = nt*16 + (lane & 15);
    const int k = kt*32 + (lane >> 4)*8 + ii;
    const float v = (k < 64) ? wih[dd*24960 + n*65 + k]
                             : whh[dd*49152 + n*128 + (k - 64)];
    const short hi = f2bf(v);
    Wg[i] = sp ? f2bf(v - bf2f(hi)) : hi;
  } else if (i < 360448) {
    const int t = i - 294912;
    const int dd = t / 32768, r = t % 32768;
    const int sp = r / 16384, r2 = r % 16384;
    const int chunk = r2 / 512, e = r2 % 512;
    const int lane = e >> 3, ii = e & 7;
    const int nt2 = chunk / 4, kt = chunk % 4;
    const int n2 = nt2*16 + (lane & 15);
    const int k = kt*32 + (lane >> 4)*8 + ii;
    const float v = (n2 < 64) ? Wx[n2*256 + dd*128 + k]
                              : Wz[(n2 - 64)*256 + dd*128 + k];
    const short hi = f2bf(v);
    W2g[t] = sp ? f2bf(v - bf2f(hi)) : hi;
  } else if (i < 361216) {
    const int t = i - 360448;
    const int dd = t / 384, g = t % 384;
    float ssum = 0.f;
    for (int f = 0; f < 65; ++f) ssum += wih[dd*24960 + g*65 + f];
    rowsum[t] = ssum;
  }
}

// ---------------------------------------------------------------------------
// K3: GRU scan, register-resident weights. Block = 64 batches x 1 dir, 8 waves.
// Wave w owns gate cols {j,128+j,256+j : j=16w+l15} + proj slice nt2=w.
// CHANGES vs prev round (latency-bound, 50k cyc/step vs ~8k issue):
//  * Ah/Ax DOUBLE-BUFFERED in LDS -> the read-drain barrier (old B2) is GONE:
//    exactly ONE __syncthreads per step (publishes h(s)+Ax(s+1) for proj(s)
//    and gates(s+1); all reads between barriers hit parity-A buffers, all
//    writes hit parity-B -> race-free with a single barrier).
//  * xraw (pre-transformed 2x-3), htyU slice, bnac hoisted to LDS once ->
//    no per-step global loads on the critical path (xraw was a 256B-stride
//    gather that re-missed L2 every step).
// LDS: 32K Ax(2) + 64K Ah(2) + 17.4K xl + 17.4K hty + 0.5K bna = 131.3 KB
// (occupancy is register-bound at 8 waves/CU, so LDS is free).
// ---------------------------------------------------------------------------
__global__ __launch_bounds__(512, 2) void k_scan(
    const short* __restrict__ fragX, const float* __restrict__ htyU,
    const float* __restrict__ xraw,
    const short* __restrict__ Wg, const short* __restrict__ W2g,
    const float* __restrict__ bih, const float* __restrict__ bhh,
    const float* __restrict__ rowsum, const float* __restrict__ bnac,
    const float* __restrict__ wih,
    float* __restrict__ wx_out, float* __restrict__ z0_out)
{
  __shared__ __align__(16) short Axb[16384];  // 2 x [sp][mt(4)][ktx(2)][512]
  __shared__ __align__(16) short Ahb[32768];  // 2 x [sp][mt(4)][kth(4)][512]
  __shared__ __align__(16) float xl[64][68];  // 2*xraw-3, [s][b_local], 16B rows
  __shared__ __align__(16) float htyl[64][68];// unscaled Hty, [s][b_local]
  __shared__ float bna[128];

  const int tid = threadIdx.x;
  const int l   = tid & 63;
  const int w   = __builtin_amdgcn_readfirstlane(tid >> 6);   // wave 0..7
  const int tile = blockIdx.x >> 1, d = blockIdx.x & 1;
  const int b0  = tile * 64;
  const int l15 = l & 15, lq = l >> 4;
  const int j   = 16*w + l15;                 // this lane's hidden unit

  const short* Wgd = Wg  + d*147456;
  const short* W2d = W2g + d*32768;
  float* wxo = wx_out + (size_t)d * (8192ull*4096ull);
  float* z0o = z0_out + (size_t)d * (8192ull*64ull);

  // ---- persistent weight fragments (VGPR-resident) ----
  s8v BR[6][2], BZ[6][2], BN[6][2], BP[4][2];
  #pragma unroll
  for (int kt = 0; kt < 6; ++kt)
    #pragma unroll
    for (int sp = 0; sp < 2; ++sp) {
      BR[kt][sp] = *(const s8v*)&Wgd[((sp*24 + w     )*6 + kt)*512 + l*8];
      BZ[kt][sp] = *(const s8v*)&Wgd[((sp*24 + 8 + w )*6 + kt)*512 + l*8];
      BN[kt][sp] = *(const s8v*)&Wgd[((sp*24 + 16 + w)*6 + kt)*512 + l*8];
    }
  #pragma unroll
  for (int kt = 0; kt < 4; ++kt)
    #pragma unroll
    for (int sp = 0; sp < 2; ++sp)
      BP[kt][sp] = *(const s8v*)&W2d[((sp*8 + w)*4 + kt)*512 + l*8];

  // ---- per-lane gate constants ----
  const float rsR = rowsum[d*384 + j];
  const float rsZ = rowsum[d*384 + 128 + j];
  const float rsN = rowsum[d*384 + 256 + j];
  const float KR  = bih[d*384 + j]       + bhh[d*384 + j];
  const float KZ  = bih[d*384 + 128 + j] + bhh[d*384 + 128 + j];
  const float KN  = bih[d*384 + 256 + j];
  const float BHN = bhh[d*384 + 256 + j];
  const float w64r = wih[d*24960 + j*65 + 64];          // f=64 (Hty) column
  const float w64z = wih[d*24960 + (128 + j)*65 + 64];
  const float w64n = wih[d*24960 + (256 + j)*65 + 64];

  // h-write geometry: value (m, j) -> A-frag slot
  const int hw_base = (j >> 5)*512 + ((j >> 3) & 3)*128 + (j & 7);

  // ---- one-time LDS preloads ----
  for (int i = tid; i < 32768; i += 512) Ahb[i] = 0;
  for (int i = tid; i < 4096; i += 512) {       // coalesced: s fastest
    const int bl = i >> 6, s = i & 63;
    xl[s][bl] = 2.f*xraw[(size_t)(b0 + bl)*64 + s] - 3.f;   // 2x - 2^RATE + 1
  }
  for (int i = tid; i < 4096; i += 512) {       // coalesced: b fastest
    const int s = i >> 6, bl = i & 63;
    htyl[s][bl] = htyU[s*8192 + b0 + bl];
  }
  if (tid < 128) bna[tid] = bnac[tid];

  f4v hprev[4], z0a[4];
  #pragma unroll
  for (int mt = 0; mt < 4; ++mt) { hprev[mt] = (f4v)0.f; z0a[mt] = (f4v)0.f; }

  {   // preload Ax(s_first) into buffer 0
    const int s0 = d ? 63 : 0;
    const short* src = fragX + (size_t)(tile*64 + s0)*8192;
    *(float4*)((char*)Axb + tid*16)        = *(const float4*)((const char*)src + tid*16);
    *(float4*)((char*)Axb + 8192 + tid*16) = *(const float4*)((const char*)src + 8192 + tid*16);
  }
  __syncthreads();

  for (int it = 0; it < 64; ++it) {
    const int s  = d ? 63 - it : it;
    const int sn = (it < 63) ? (d ? s - 1 : s + 1) : s;

    // double-buffer bases (wave-uniform LDS offsets)
    short* AxR = Axb + ((it & 1) << 13);        // X(s)     : read
    short* AxW = Axb + (((it + 1) & 1) << 13);  // X(s+1)   : write
    short* AhR = Ahb + (((it + 1) & 1) << 14);  // h(s-1)   : read (gates)
    short* AhW = Ahb + ((it & 1) << 14);        // h(s)     : write + proj read

    // register-prefetch next step's Ax (latency hidden under gate GEMM)
    const short* srcn = fragX + (size_t)(tile*64 + sn)*8192;
    const float4 pf0 = *(const float4*)((const char*)srcn + tid*16);
    const float4 pf1 = *(const float4*)((const char*)srcn + 8192 + tid*16);

    const float a_s = bna[s], c_s = bna[64 + s];
    const float crK = c_s*rsR + KR;
    const float czK = c_s*rsZ + KZ;
    const float cnK = c_s*rsN + KN;

    // ---- gate GEMM + gates, per M-tile ----
    #pragma unroll
    for (int mt = 0; mt < 4; ++mt) {
      f4v Crx = (f4v)0.f, Czx = (f4v)0.f, Cnx = (f4v)0.f;
      f4v Crh = (f4v)0.f, Czh = (f4v)0.f, Cnh = (f4v)0.f;
      #pragma unroll
      for (int kt = 0; kt < 2; ++kt) {        // x part (K=64, unscaled)
        const s8v axh = *(const s8v*)&AxR[mt*1024 + kt*512 + l*8];
        const s8v axl = *(const s8v*)&AxR[4096 + mt*1024 + kt*512 + l*8];
        Crx = MFMA(axh, BR[kt][0], Crx); Crx = MFMA(axh, BR[kt][1], Crx); Crx = MFMA(axl, BR[kt][0], Crx);
        Czx = MFMA(axh, BZ[kt][0], Czx); Czx = MFMA(axh, BZ[kt][1], Czx); Czx = MFMA(axl, BZ[kt][0], Czx);
        Cnx = MFMA(axh, BN[kt][0], Cnx); Cnx = MFMA(axh, BN[kt][1], Cnx); Cnx = MFMA(axl, BN[kt][0], Cnx);
      }
      #pragma unroll
      for (int kh = 0; kh < 4; ++kh) {        // h part (K=128)
        const s8v ahh = *(const s8v*)&AhR[mt*2048 + kh*512 + l*8];
        const s8v ahl = *(const s8v*)&AhR[8192 + mt*2048 + kh*512 + l*8];
        const int kt = 2 + kh;
        Crh = MFMA(ahh, BR[kt][0], Crh); Crh = MFMA(ahh, BR[kt][1], Crh); Crh = MFMA(ahl, BR[kt][0], Crh);
        Czh = MFMA(ahh, BZ[kt][0], Czh); Czh = MFMA(ahh, BZ[kt][1], Czh); Czh = MFMA(ahl, BZ[kt][0], Czh);
        Cnh = MFMA(ahh, BN[kt][0], Cnh); Cnh = MFMA(ahh, BN[kt][1], Cnh); Cnh = MFMA(ahl, BN[kt][0], Cnh);
      }
      // exact fp32 rank-1 for the Hty channel (LDS-sourced, joins x-part)
      const float4 av4 = *(const float4*)&htyl[s][mt*16 + lq*4];
      f4v av; av[0]=av4.x; av[1]=av4.y; av[2]=av4.z; av[3]=av4.w;
      Crx += av * w64r; Czx += av * w64z; Cnx += av * w64n;
      // gates: r=sig, z=sig, n=tanh(xn + r*hn); BN scale a_s applied here
      #pragma unroll
      for (int e = 0; e < 4; ++e) {
        const float rr  = 1.f/(1.f + __expf(-(a_s*Crx[e] + Crh[e] + crK)));
        const float zz  = 1.f/(1.f + __expf(-(a_s*Czx[e] + Czh[e] + czK)));
        const float pre = a_s*Cnx[e] + cnK + rr*(Cnh[e] + BHN);
        const float ax2 = fabsf(pre);
        const float ee  = __expf(-2.f*ax2);
        const float nn  = copysignf((1.f - ee)/(1.f + ee), pre);
        hprev[mt][e] = (1.f - zz)*nn + zz*hprev[mt][e];
      }
    }

    // write h(s) hi/lo into AhW (other buffer: no read-drain barrier needed);
    // write prefetched Ax(s+1) into AxW
    #pragma unroll
    for (int mt = 0; mt < 4; ++mt)
      #pragma unroll
      for (int e = 0; e < 4; ++e) {
        const float hv = hprev[mt][e];
        const short hi = f2bf(hv);
        const int ad = mt*2048 + hw_base + (lq*4 + e)*8;
        AhW[ad] = hi;
        AhW[8192 + ad] = f2bf(hv - bf2f(hi));
      }
    *(float4*)((char*)AxW + tid*16)        = pf0;
    *(float4*)((char*)AxW + 8192 + tid*16) = pf1;
    __syncthreads();   // the ONLY barrier: h(s), Ax(s+1) visible to all waves

    // ---- projection: waves 0-3 -> wx cols, waves 4-7 -> wz (z0 accum) ----
    #pragma unroll
    for (int mt = 0; mt < 4; ++mt) {
      f4v Cp = (f4v)0.f;
      #pragma unroll
      for (int kt = 0; kt < 4; ++kt) {
        const s8v ahh = *(const s8v*)&AhW[mt*2048 + kt*512 + l*8];
        const s8v ahl = *(const s8v*)&AhW[8192 + mt*2048 + kt*512 + l*8];
        Cp = MFMA(ahh, BP[kt][0], Cp);
        Cp = MFMA(ahh, BP[kt][1], Cp);
        Cp = MFMA(ahl, BP[kt][0], Cp);
      }
      if (w < 4) {
        #pragma unroll
        for (int e = 0; e < 4; ++e)
          wxo[(size_t)(b0 + mt*16 + lq*4 + e)*4096 + s*64 + 16*w + l15] = Cp[e];
      } else {
        const float4 xh4 = *(const float4*)&xl[s][mt*16 + lq*4];  // 2x-3, LDS
        f4v xh; xh[0]=xh4.x; xh[1]=xh4.y; xh[2]=xh4.z; xh[3]=xh4.w;
        z0a[mt] += xh * Cp;
      }
    }
  }
  if (w >= 4) {
    #pragma unroll
    for (int mt = 0; mt < 4; ++mt)
      #pragma unroll
      for (int e = 0; e < 4; ++e)
        z0o[(size_t)(b0 + mt*16 + lq*4 + e)*64 + 16*(w-4) + l15] = z0a[mt][e];
  }
}

// ---------------------------------------------------------------------------
// K4: GD loop via Gram trick: tmp=H@wx; ww=tmp^T tmp; wh=tmp^T y (no HtH).
// ---------------------------------------------------------------------------
__global__ __launch_bounds__(256) void k_gd(
    const float* __restrict__ Hm, const float* __restrict__ y,
    const float* __restrict__ wxf, const float* __restrict__ wxb,
    const float* __restrict__ z0f, const float* __restrict__ z0b,
    float* __restrict__ out)
{
  __shared__ __align__(16) float Hl[64][68];    // H[r][t]; reused as ww[zi][zj]
  __shared__ __align__(16) float wx[64][68];    // wx[s][z]
  __shared__ __align__(16) float tmp[64][68];   // (H@wx)[r][z]
  __shared__ float yl[64], wh[64], zv[64];
  const int b = blockIdx.x;
  const int tid = threadIdx.x;
  const float* Hb = Hm + (size_t)b*4096;
  for (int i = tid; i < 4096; i += 256) {
    Hl[i>>6][i&63] = Hb[i];
    wx[i>>6][i&63] = wxf[(size_t)b*4096 + i] + wxb[(size_t)b*4096 + i];
  }
  if (tid < 64) {
    yl[tid] = y[b*64+tid];
    zv[tid] = z0f[(size_t)b*64+tid] + z0b[(size_t)b*64+tid];
  }
  __syncthreads();
  const int zq = tid & 15, tq = tid >> 4;
  #pragma unroll
  for (int rr = 0; rr < 4; ++rr) {             // tmp = H @ wx
    const int r = 4*tq + rr;
    float4 a = make_float4(0.f,0.f,0.f,0.f);
    for (int t = 0; t < 64; ++t) fma4(a, Hl[r][t], *(const float4*)&wx[t][4*zq]);
    *(float4*)&tmp[r][4*zq] = a;
  }
  __syncthreads();                              // Hl reads done -> reuse as ww
  float (*ww)[68] = Hl;
  #pragma unroll
  for (int ii = 0; ii < 4; ++ii) {              // ww = tmp^T tmp
    const int zi = 4*tq + ii;
    float4 a = make_float4(0.f,0.f,0.f,0.f);
    for (int r = 0; r < 64; ++r) fma4(a, tmp[r][zi], *(const float4*)&tmp[r][4*zq]);
    *(float4*)&ww[zi][4*zq] = a;
  }
  if (tid < 64) {                               // wh = tmp^T y
    float acc = 0.f;
    for (int r = 0; r < 64; ++r) acc += tmp[r][tid]*yl[r];
    wh[tid] = acc;
  }
  __syncthreads();
  for (int itr = 0; itr < 10; ++itr) {          // z += 2e-6*(wh - ww@z)
    float nz = 0.f;
    if (tid < 64) {
      float mv = 0.f;
      for (int k2 = 0; k2 < 64; ++k2) mv += ww[tid][k2]*zv[k2];
      nz = zv[tid] + 2e-6f*(wh[tid] - mv);
    }
    __syncthreads();
    if (tid < 64) zv[tid] = nz;
    __syncthreads();
  }
  if (tid < 64) {                               // out = wx @ z
    float o = 0.f;
    for (int z2 = 0; z2 < 64; ++z2) o += wx[tid][z2]*zv[z2];
    out[(size_t)b*64 + tid] = o;
  }
}

// ---------------------------------------------------------------------------
extern "C" void kernel_launch(void* const* d_in, const int* in_sizes, int n_in,
                              void* d_out, int out_size, void* d_ws, size_t ws_size,
                              hipStream_t stream)
{
  const float* y    = (const float*)d_in[0];
  const float* Hm   = (const float*)d_in[1];
  const float* xraw = (const float*)d_in[2];
  const float* wih  = (const float*)d_in[3];
  const float* whh  = (const float*)d_in[4];
  const float* bih  = (const float*)d_in[5];
  const float* bhh  = (const float*)d_in[6];
  const float* Wz   = (const float*)d_in[7];
  const float* Wx   = (const float*)d_in[8];
  const float* gam  = (const float*)d_in[9];
  const float* bet  = (const float*)d_in[10];
  float* out = (float*)d_out;
  float* ws  = (float*)d_ws;

  // ws layout (floats), total = 102,419,328 floats = 409.68 MB (== round-3
  // proven footprint). No aliasing anywhere.
  float* wxf   = ws;                        // 33,554,432
  float* wxb   = wxf + 33554432ull;         // 33,554,432
  float* z0f   = wxb + 33554432ull;         // 524,288
  float* z0b   = z0f + 524288ull;           // 524,288
  float* htyU  = z0b + 524288ull;           // 524,288  [s][b] unscaled Hty
  float* rows  = htyU + 524288ull;          // 768
  float* bnacc = rows + 768ull;             // 2,048 (spaced x16)
  float* bnac  = bnacc + 2048ull;           // 128
  short* Wgs   = (short*)(bnac + 128ull);   // 294,912 shorts
  short* W2gs  = Wgs + 294912ull;           // 65,536 shorts
  short* fragX = W2gs + 65536ull;           // 67,108,864 shorts (134 MB)

  hipMemsetAsync(bnacc, 0, 2048*sizeof(float), stream);
  k_feats <<<8192, 256, 0, stream>>>(Hm, y, fragX, htyU, bnacc);
  k_prep  <<<1412, 256, 0, stream>>>(wih, whh, Wz, Wx, Wgs, W2gs, rows);
  k_bnfin <<<1, 64, 0, stream>>>(bnacc, gam, bet, bnac);
  k_scan  <<<256, 512, 0, stream>>>(fragX, htyU, xraw, Wgs, W2gs,
                                    bih, bhh, rows, bnac, wih, wxf, z0f);
  k_gd    <<<8192, 256, 0, stream>>>(Hm, y, wxf, wxb, z0f, z0b, out);
}